// Round 8
// baseline (45.424 us; speedup 1.0000x reference)
//
#include <hip/hip_runtime.h>
#include <math.h>

#define NPV 3072
#define LDP 3073
#define EPSF 1e-8f
#define NMOM 52     // [0..6] w-moments (Sw, Sx1,Sy1,Sq1, Sx2,Sy2,Sq2), [7..51] 45 sym tensor
#define NBLK 768    // row-moment blocks (4 rows each)
#define CAP 24      // per-row candidate capacity (col-test passers ~Poisson(3))

// Branchless insert of v into sorted-descending triple (a >= b >= c).
#define INS3(v, a, b, c) do { \
    float _m1 = fminf((a), (v)); (a) = fmaxf((a), (v)); \
    float _m2 = fminf((b), _m1); (b) = fmaxf((b), _m1); \
    (c) = fmaxf((c), _m2); } while (0)

#define MRG3(x, y, z, a, b, c) do { \
    INS3((x), a, b, c); INS3((y), a, b, c); INS3((z), a, b, c); } while (0)

__device__ __forceinline__ void kinv6(const float* __restrict__ Kmat,
        float& ki0, float& ki1, float& ki2, float& ki3, float& ki4, float& ki5)
{
    float k00 = Kmat[0], k01 = Kmat[1], k02 = Kmat[2];
    float k10 = Kmat[3], k11 = Kmat[4], k12 = Kmat[5];
    float k20 = Kmat[6], k21 = Kmat[7], k22 = Kmat[8];
    float det = k00 * (k11 * k22 - k12 * k21) - k01 * (k10 * k22 - k12 * k20) + k02 * (k10 * k21 - k11 * k20);
    float id = 1.0f / det;
    ki0 = (k11 * k22 - k12 * k21) * id; ki1 = (k02 * k21 - k01 * k22) * id; ki2 = (k01 * k12 - k02 * k11) * id;
    ki3 = (k12 * k20 - k10 * k22) * id; ki4 = (k00 * k22 - k02 * k20) * id; ki5 = (k02 * k10 - k00 * k12) * id;
}

// Pure column top-3 partials over a row segment. grid (NPV/256, nseg). No atomics.
__global__ __launch_bounds__(256) void k_col_pass(const float* __restrict__ P,
        float4* __restrict__ part, int segrows)
{
    int j = blockIdx.x * 256 + threadIdx.x;
    int i0 = blockIdx.y * segrows;
    float a0 = -1e30f, b0 = -1e30f, c0 = -1e30f;
    float a1 = -1e30f, b1 = -1e30f, c1 = -1e30f;
    float a2 = -1e30f, b2 = -1e30f, c2 = -1e30f;
    float a3 = -1e30f, b3 = -1e30f, c3 = -1e30f;
    float a4 = -1e30f, b4 = -1e30f, c4 = -1e30f;
    float a5 = -1e30f, b5 = -1e30f, c5 = -1e30f;
    float a6 = -1e30f, b6 = -1e30f, c6 = -1e30f;
    float a7 = -1e30f, b7 = -1e30f, c7 = -1e30f;
    for (int r = 0; r < segrows; r += 8) {
        const float* col = P + (size_t)(i0 + r) * LDP + j;
        float v0 = col[0 * LDP];
        float v1 = col[1 * LDP];
        float v2 = col[2 * LDP];
        float v3 = col[3 * LDP];
        float v4 = col[4 * LDP];
        float v5 = col[5 * LDP];
        float v6 = col[6 * LDP];
        float v7 = col[7 * LDP];
        INS3(v0, a0, b0, c0);
        INS3(v1, a1, b1, c1);
        INS3(v2, a2, b2, c2);
        INS3(v3, a3, b3, c3);
        INS3(v4, a4, b4, c4);
        INS3(v5, a5, b5, c5);
        INS3(v6, a6, b6, c6);
        INS3(v7, a7, b7, c7);
    }
    MRG3(a1, b1, c1, a0, b0, c0);
    MRG3(a2, b2, c2, a0, b0, c0);
    MRG3(a3, b3, c3, a0, b0, c0);
    MRG3(a4, b4, c4, a0, b0, c0);
    MRG3(a5, b5, c5, a0, b0, c0);
    MRG3(a6, b6, c6, a0, b0, c0);
    MRG3(a7, b7, c7, a0, b0, c0);
    part[(size_t)blockIdx.y * NPV + j] = make_float4(a0, b0, c0, 0.f);
}

// 16 threads per column, NSEG/16 segments each, 4-step shfl merge.
template<int NSEG>
__global__ __launch_bounds__(256) void k_col_merge(const float4* __restrict__ part,
        float* __restrict__ tc)
{
    int sub = threadIdx.x & 15;
    int j = blockIdx.x * 16 + (threadIdx.x >> 4);
    constexpr int CNT = NSEG / 16;
    float4 buf[CNT];
    #pragma unroll
    for (int k = 0; k < CNT; ++k)
        buf[k] = part[(size_t)(sub + (k << 4)) * NPV + j];
    float a = -1e30f, b = -1e30f, c = -1e30f;
    #pragma unroll
    for (int k = 0; k < CNT; ++k) MRG3(buf[k].x, buf[k].y, buf[k].z, a, b, c);
    #pragma unroll
    for (int off = 1; off < 16; off <<= 1) {
        float xa = __shfl_xor(a, off);
        float xb = __shfl_xor(b, off);
        float xc = __shfl_xor(c, off);
        MRG3(xa, xb, xc, a, b, c);
    }
    if (sub == 0) tc[j] = c;
}

// Per-candidate contribution to the 52 moments (mean-shifted coords).
__device__ __forceinline__ void acc_pair(float* m, float w, float xs1, float ys1,
                                         float xs2, float ys2)
{
    m[0] += w;
    m[1] += w * xs1; m[2] += w * ys1; m[3] += w * (xs1 * xs1 + ys1 * ys1);
    m[4] += w * xs2; m[5] += w * ys2; m[6] += w * (xs2 * xs2 + ys2 * ys2);
    float a[9] = { xs1 * xs2, xs1 * ys2, xs1, ys1 * xs2, ys1 * ys2, ys1, xs2, ys2, 1.f };
    int idx = 7;
    #pragma unroll
    for (int u = 0; u < 9; ++u) {
        float wa = w * a[u];
        #pragma unroll
        for (int v = u; v < 9; ++v) { m[idx] = fmaf(wa, a[v], m[idx]); ++idx; }
    }
}

// Fused row pass: one wave per row (4/block). Phase 1: branchless row top-3 +
// ballot-compacted collection of {v >= tc[j], v > 0.01} entries into LDS.
// Phase 2: apply row-3rd test, accumulate 52 raw moments, reduce, write partial.
__global__ __launch_bounds__(256) void k_row_mom(const float* __restrict__ P,
        const float* __restrict__ tc, const float* __restrict__ Kmat,
        float* __restrict__ momp)
{
    __shared__ int   jsl[4][CAP];
    __shared__ float vsl[4][CAP];
    __shared__ float sPart[4][NMOM];
    int lane = threadIdx.x & 63;
    int wid  = threadIdx.x >> 6;
    int i = blockIdx.x * 4 + wid;
    const float* row = P + (size_t)i * LDP;
    unsigned long long ltm = (1ull << lane) - 1ull;

    float a0 = -1e30f, b0 = -1e30f, c0 = -1e30f;
    float a1 = -1e30f, b1 = -1e30f, c1 = -1e30f;
    float a2 = -1e30f, b2 = -1e30f, c2 = -1e30f;
    float a3 = -1e30f, b3 = -1e30f, c3 = -1e30f;
    int cnt = 0;

#define CTEST(vk, tk, jk) do { \
        bool _p = ((vk) >= (tk)) && ((vk) > 0.01f); \
        unsigned long long _m = __ballot(_p); \
        if (_p) { \
            int _pos = cnt + (int)__popcll(_m & ltm); \
            if (_pos < CAP) { jsl[wid][_pos] = (jk); vsl[wid][_pos] = (vk); } \
        } \
        cnt += (int)__popcll(_m); } while (0)

    #pragma unroll
    for (int r = 0; r < 48; r += 4) {
        float v0 = row[(r + 0) * 64 + lane];
        float v1 = row[(r + 1) * 64 + lane];
        float v2 = row[(r + 2) * 64 + lane];
        float v3 = row[(r + 3) * 64 + lane];
        float t0 = tc[(r + 0) * 64 + lane];
        float t1 = tc[(r + 1) * 64 + lane];
        float t2 = tc[(r + 2) * 64 + lane];
        float t3 = tc[(r + 3) * 64 + lane];
        INS3(v0, a0, b0, c0);
        INS3(v1, a1, b1, c1);
        INS3(v2, a2, b2, c2);
        INS3(v3, a3, b3, c3);
        CTEST(v0, t0, (r + 0) * 64 + lane);
        CTEST(v1, t1, (r + 1) * 64 + lane);
        CTEST(v2, t2, (r + 2) * 64 + lane);
        CTEST(v3, t3, (r + 3) * 64 + lane);
    }
#undef CTEST
    MRG3(a1, b1, c1, a0, b0, c0);
    MRG3(a2, b2, c2, a0, b0, c0);
    MRG3(a3, b3, c3, a0, b0, c0);
    #pragma unroll
    for (int off = 1; off < 64; off <<= 1) {
        float xa = __shfl_xor(a0, off);
        float xb = __shfl_xor(b0, off);
        float xc = __shfl_xor(c0, off);
        MRG3(xa, xb, xc, a0, b0, c0);
    }
    // c0 = row's 3rd-largest (uniform across wave)

    float ki0, ki1, ki2, ki3, ki4, ki5;
    kinv6(Kmat, ki0, ki1, ki2, ki3, ki4, ki5);

    float mloc[NMOM];
    #pragma unroll
    for (int k = 0; k < NMOM; ++k) mloc[k] = 0.f;
    int n = cnt < CAP ? cnt : CAP;
    if (lane < n) {
        int j = jsl[wid][lane];
        float w = vsl[wid][lane];
        if (w >= c0) {
            float xg = (float)(i & 63) - 31.5f, yg = (float)(i >> 6) - 23.5f;
            float xs1 = ki0 * xg + ki1 * yg;
            float ys1 = ki3 * xg + ki4 * yg;
            float xj = (float)(j & 63) - 31.5f, yj = (float)(j >> 6) - 23.5f;
            float xs2 = ki0 * xj + ki1 * yj;
            float ys2 = ki3 * xj + ki4 * yj;
            acc_pair(mloc, w, xs1, ys1, xs2, ys2);
        }
    }
    #pragma unroll
    for (int k = 0; k < NMOM; ++k) {
        #pragma unroll
        for (int off = 32; off; off >>= 1) mloc[k] += __shfl_xor(mloc[k], off);
    }
    if (lane == 0) {
        #pragma unroll
        for (int k = 0; k < NMOM; ++k) sPart[wid][k] = mloc[k];
    }
    __syncthreads();
    if (threadIdx.x < NMOM)
        momp[(size_t)blockIdx.x * 64 + threadIdx.x] =
            sPart[0][threadIdx.x] + sPart[1][threadIdx.x] +
            sPart[2][threadIdx.x] + sPart[3][threadIdx.x];
}

__device__ __forceinline__ void mm3r(const float* A, const float* B, float* C) {
    #pragma unroll
    for (int r = 0; r < 3; ++r)
        #pragma unroll
        for (int c = 0; c < 3; ++c)
            C[r * 3 + c] = A[r * 3 + 0] * B[0 + c] + A[r * 3 + 1] * B[3 + c] + A[r * 3 + 2] * B[6 + c];
}

__device__ __forceinline__ float det3(const float* M) {
    return M[0] * (M[4] * M[8] - M[5] * M[7])
         - M[1] * (M[3] * M[8] - M[5] * M[6])
         + M[2] * (M[3] * M[7] - M[4] * M[6]);
}

// Single block: 768-partial reduce + congruence transform + matrix-power tails.
__global__ __launch_bounds__(1024) void k_tail(const float* __restrict__ Kmat,
        const float* __restrict__ momp, float* __restrict__ out)
{
    __shared__ float sRed[16][64];
    __shared__ float sMom[NMOM];
    __shared__ float sM[81], sY[81], sP[81], sT[81];
    __shared__ float sT1[9], sT2[9];
    int t = threadIdx.x;

    // Reduce NBLK x 52 partials: 16 chunks of 48, coalesced per (chunk, part).
    {
        int c = t >> 6, k = t & 63;
        float s = 0.f;
        #pragma unroll 8
        for (int p = 0; p < NBLK / 16; ++p)
            s += momp[(size_t)(c * (NBLK / 16) + p) * 64 + k];
        sRed[c][k] = s;
    }
    __syncthreads();
    if (t < NMOM) {
        float s = 0.f;
        #pragma unroll
        for (int c = 0; c < 16; ++c) s += sRed[c][t];
        sMom[t] = s;
    }
    __syncthreads();

    float ki0, ki1, ki2, ki3, ki4, ki5;
    kinv6(Kmat, ki0, ki1, ki2, ki3, ki4, ki5);
    float u0x = ki0 * 31.5f + ki1 * 23.5f + ki2;
    float u0y = ki3 * 31.5f + ki4 * 23.5f + ki5;

    float Sw = sMom[0];
    float ws = Sw + EPSF;
    float c1x = sMom[1] / ws, c1y = sMom[2] / ws;
    float c2x = sMom[4] / ws, c2y = sMom[5] / ws;
    float q1 = (sMom[3] - 2.f * (c1x * sMom[1] + c1y * sMom[2]) + (c1x * c1x + c1y * c1y) * Sw) / ws;
    float q2 = (sMom[6] - 2.f * (c2x * sMom[4] + c2y * sMom[5]) + (c2x * c2x + c2y * c2y) * Sw) / ws;
    float md1 = sqrtf(fmaxf(q1, 0.f) + EPSF);
    float md2 = sqrtf(fmaxf(q2, 0.f) + EPSF);
    float s1 = 1.4142135623730951f / (md1 + EPSF);
    float s2 = 1.4142135623730951f / (md2 + EPSF);

    if (t < 81) {
        int r = t / 9, c = t % 9;
        int u = r < c ? r : c, v = r < c ? c : r;
        int idx = 7 + u * 9 - (u * (u + 1)) / 2 + v;
        sM[t] = sMom[idx];
    }
    if (t == 0) {
        sT1[0] = s1; sT1[1] = 0.f; sT1[2] = -s1 * c1x;
        sT1[3] = 0.f; sT1[4] = s1; sT1[5] = -s1 * c1y;
        sT1[6] = 0.f; sT1[7] = 0.f; sT1[8] = 1.f;
        sT2[0] = s2; sT2[1] = 0.f; sT2[2] = -s2 * c2x;
        sT2[3] = 0.f; sT2[4] = s2; sT2[5] = -s2 * c2y;
        sT2[6] = 0.f; sT2[7] = 0.f; sT2[8] = 1.f;
    }
    __syncthreads();

    if (t < 81) {
        int k = t / 9, c = t % 9;
        float s = 0.f;
        #pragma unroll
        for (int l = 0; l < 9; ++l)
            s = fmaf(sM[k * 9 + l], sT1[(c / 3) * 3 + (l / 3)] * sT2[(c % 3) * 3 + (l % 3)], s);
        sY[t] = s;
    }
    __syncthreads();
    if (t < 81) {
        int r = t / 9, c = t % 9;
        float s = 0.f;
        #pragma unroll
        for (int k = 0; k < 9; ++k)
            s = fmaf(sT1[(r / 3) * 3 + (k / 3)] * sT2[(r % 3) * 3 + (k % 3)], sY[k * 9 + c], s);
        sP[t] = s;
    }
    __syncthreads();
    if (t < 81) {
        int r = t / 9, c = t % 9;
        float lam = sP[0] + sP[10] + sP[20] + sP[30] + sP[40] + sP[50] + sP[60] + sP[70] + sP[80];
        float il = 1.f / (lam + 1e-30f);
        sM[t] = ((r == c ? lam : 0.f) - sP[t]) * il;
    }
    __syncthreads();

#define MM81(DST, A, B) \
    if (t < 81) { \
        int _r = t / 9, _c = t % 9; \
        float _s = 0.f; \
        _Pragma("unroll") \
        for (int _k = 0; _k < 9; ++_k) _s = fmaf(A[_r * 9 + _k], B[_k * 9 + _c], _s); \
        DST[t] = _s; \
    } \
    __syncthreads();

    MM81(sY, sM, sM)   // P2   (kept)
    MM81(sP, sY, sY)   // P4
    MM81(sT, sP, sP)   // P8
    MM81(sP, sT, sT)   // P16  (kept)
    MM81(sT, sP, sP)   // P32
    MM81(sM, sT, sP)   // R  = P32*P16
    MM81(sT, sM, sY)   // P50 = R*P2

    if (t < 64) {
        float v9[9];
        float nrm = 0.f;
        #pragma unroll
        for (int r = 0; r < 9; ++r) {
            float s = 0.f;
            #pragma unroll
            for (int c = 0; c < 9; ++c) s += sT[r * 9 + c];
            v9[r] = s * (1.f / 3.f);
            nrm += v9[r] * v9[r];
        }
        nrm = sqrtf(nrm) + EPSF;
        #pragma unroll
        for (int r = 0; r < 9; ++r) v9[r] /= nrm;

        float C1x = c1x + u0x, C1y = c1y + u0y;
        float C2x = c2x + u0x, C2y = c2y + u0y;
        float T1f[9] = { s1, 0.f, -s1 * C1x, 0.f, s1, -s1 * C1y, 0.f, 0.f, 1.f };
        float T2t[9] = { s2, 0.f, 0.f, 0.f, s2, 0.f, -s2 * C2x, -s2 * C2y, 1.f };
        float M1[9], Ee[9];
        mm3r(v9, T1f, M1);
        mm3r(T2t, M1, Ee);

        float B[9];
        #pragma unroll
        for (int r = 0; r < 3; ++r)
            #pragma unroll
            for (int c = 0; c < 3; ++c)
                B[r * 3 + c] = Ee[r] * Ee[c] + Ee[3 + r] * Ee[3 + c] + Ee[6 + r] * Ee[6 + c];
        float lam3 = B[0] + B[4] + B[8];
        float il3 = 1.f / (lam3 + 1e-30f);

        int parity = t & 1;
        float P1[9];
        #pragma unroll
        for (int k = 0; k < 9; ++k) {
            float d = (k == 0 || k == 4 || k == 8) ? lam3 : 0.f;
            P1[k] = (parity ? (d - B[k]) : B[k]) * il3;
        }
        float P2[9], P4[9], P8[9], P16[9], P32[9], R1[9], P50[9];
        mm3r(P1, P1, P2);
        mm3r(P2, P2, P4);
        mm3r(P4, P4, P8);
        mm3r(P8, P8, P16);
        mm3r(P16, P16, P32);
        mm3r(P32, P16, R1);
        mm3r(R1, P2, P50);
        float vx = (P50[0] + P50[1] + P50[2]) * 0.57735026918962584f;
        float vy = (P50[3] + P50[4] + P50[5]) * 0.57735026918962584f;
        float vz = (P50[6] + P50[7] + P50[8]) * 0.57735026918962584f;
        float vn = sqrtf(vx * vx + vy * vy + vz * vz) + EPSF;
        vx /= vn; vy /= vn; vz /= vn;

        float v3x = __shfl(vx, 1), v3y = __shfl(vy, 1), v3z = __shfl(vz, 1);

        if (t == 0) {
            float v1[3] = { vx, vy, vz };
            float v3[3] = { v3x, v3y, v3z };
            float v2[3];
            v2[0] = v3[1] * v1[2] - v3[2] * v1[1];
            v2[1] = v3[2] * v1[0] - v3[0] * v1[2];
            v2[2] = v3[0] * v1[1] - v3[1] * v1[0];
            float n2 = sqrtf(v2[0] * v2[0] + v2[1] * v2[1] + v2[2] * v2[2]) + EPSF;
            v2[0] /= n2; v2[1] /= n2; v2[2] /= n2;
            float V[9];
            #pragma unroll
            for (int r = 0; r < 3; ++r) { V[r * 3 + 0] = v1[r]; V[r * 3 + 1] = v2[r]; V[r * 3 + 2] = v3[r]; }
            float dV = det3(V);
            float sV = (dV > 0.f) ? 1.f : ((dV < 0.f) ? -1.f : 0.f);
            V[2] *= sV; V[5] *= sV; V[8] *= sV;
            float Ev1[3], Ev2[3];
            #pragma unroll
            for (int r = 0; r < 3; ++r) {
                Ev1[r] = Ee[r * 3] * V[0] + Ee[r * 3 + 1] * V[3] + Ee[r * 3 + 2] * V[6];
                Ev2[r] = Ee[r * 3] * V[1] + Ee[r * 3 + 1] * V[4] + Ee[r * 3 + 2] * V[7];
            }
            float s1n = sqrtf(Ev1[0] * Ev1[0] + Ev1[1] * Ev1[1] + Ev1[2] * Ev1[2]);
            float s2n = sqrtf(Ev2[0] * Ev2[0] + Ev2[1] * Ev2[1] + Ev2[2] * Ev2[2]);
            float s_avg = (s1n + s2n) * 0.5f;
            float u1[3], u2[3];
            #pragma unroll
            for (int r = 0; r < 3; ++r) { u1[r] = Ev1[r] / (s1n + EPSF); u2[r] = Ev2[r] / (s2n + EPSF); }
            #pragma unroll
            for (int r = 0; r < 3; ++r)
                #pragma unroll
                for (int c = 0; c < 3; ++c)
                    out[r * 3 + c] = s_avg * (u1[r] * V[c * 3 + 0] + u2[r] * V[c * 3 + 1]);
        }
    }
}

extern "C" void kernel_launch(void* const* d_in, const int* in_sizes, int n_in,
                              void* d_out, int out_size, void* d_ws, size_t ws_size,
                              hipStream_t stream)
{
    const float* P = (const float*)d_in[0];
    const float* K = (const float*)d_in[1];
    float* out = (float*)d_out;

    float* fws   = (float*)d_ws;
    float* tc    = fws;                          // NPV
    float* momp  = tc + NPV;                     // NBLK*64
    float4* part = (float4*)(momp + NBLK * 64);  // NPV*nseg float4 (offset 52224 floats, 16B-aligned)

    size_t fixed_bytes = ((size_t)NPV + NBLK * 64) * sizeof(float);
    int nseg = 16;
    for (int cand = 128; cand >= 16; cand >>= 1) {
        if (ws_size >= fixed_bytes + (size_t)cand * NPV * sizeof(float4)) { nseg = cand; break; }
    }
    int segrows = NPV / nseg;

    dim3 g1(NPV / 256, nseg);
    k_col_pass<<<g1, 256, 0, stream>>>(P, part, segrows);
    switch (nseg) {
        case 128: k_col_merge<128><<<NPV / 16, 256, 0, stream>>>(part, tc); break;
        case 64:  k_col_merge<64><<<NPV / 16, 256, 0, stream>>>(part, tc); break;
        case 32:  k_col_merge<32><<<NPV / 16, 256, 0, stream>>>(part, tc); break;
        default:  k_col_merge<16><<<NPV / 16, 256, 0, stream>>>(part, tc); break;
    }
    k_row_mom<<<NBLK, 256, 0, stream>>>(P, tc, K, momp);
    k_tail<<<1, 1024, 0, stream>>>(K, momp, out);
}